// Round 4
// baseline (221.918 us; speedup 1.0000x reference)
//
#include <hip/hip_runtime.h>
#include <hip/hip_bf16.h>
#include <stdint.h>

#define BB_ 2
#define SS_ 2048
#define DIM_ 512
#define NH_ 8
#define QK_ 128
#define VD_ 128

typedef __attribute__((ext_vector_type(8))) short bf16x8;
typedef __attribute__((ext_vector_type(4))) float f32x4;
typedef __attribute__((ext_vector_type(8))) unsigned short ushort8;
typedef __attribute__((ext_vector_type(4))) unsigned short ushort4v;

__device__ __forceinline__ unsigned short f2bf(float f) {
  union { float f; unsigned int u; } v; v.f = f;
  unsigned int r = v.u + 0x7FFFu + ((v.u >> 16) & 1u);  // RNE
  return (unsigned short)(r >> 16);
}

__device__ __forceinline__ f32x4 mfma16(bf16x8 a, bf16x8 b, f32x4 c) {
  return __builtin_amdgcn_mfma_f32_16x16x32_bf16(a, b, c, 0, 0, 0);
}

// ---------------- convert / transpose kernels ----------------

__global__ void k_convert_x(const float* __restrict__ x, unsigned short* __restrict__ xb, int n4) {
  int i = blockIdx.x * blockDim.x + threadIdx.x;
  if (i < n4) {
    float4 v = reinterpret_cast<const float4*>(x)[i];
    ushort4v o;
    o[0] = f2bf(v.x); o[1] = f2bf(v.y); o[2] = f2bf(v.z); o[3] = f2bf(v.w);
    reinterpret_cast<ushort4v*>(xb)[i] = o;
  }
}

// src [R][C] fp32 -> dst [C][R] bf16 ; grid (C/64, R/64), block 256
__global__ void k_transpose_cvt(const float* __restrict__ src, unsigned short* __restrict__ dst,
                                int R, int C) {
  __shared__ float t[64][65];
  const int c0 = blockIdx.x * 64, r0 = blockIdx.y * 64;
  const int tid = threadIdx.x;
  const int rr = tid >> 4, cc4 = (tid & 15) * 4;
#pragma unroll
  for (int p = 0; p < 4; p++) {
    float4 v = *reinterpret_cast<const float4*>(src + (size_t)(r0 + rr + p * 16) * C + c0 + cc4);
    t[rr + p * 16][cc4 + 0] = v.x; t[rr + p * 16][cc4 + 1] = v.y;
    t[rr + p * 16][cc4 + 2] = v.z; t[rr + p * 16][cc4 + 3] = v.w;
  }
  __syncthreads();
  const int cl = tid >> 2, rb = (tid & 3) * 16;
#pragma unroll
  for (int g = 0; g < 2; g++) {
    ushort8 o;
#pragma unroll
    for (int j = 0; j < 8; j++) o[j] = f2bf(t[rb + g * 8 + j][cl]);
    *reinterpret_cast<ushort8*>(dst + (size_t)(c0 + cl) * R + r0 + rb + g * 8) = o;
  }
}

__global__ void k_concat_bias(const float* __restrict__ bq, const float* __restrict__ bk,
                              const float* __restrict__ bv, float* __restrict__ out) {
  int i = blockIdx.x * blockDim.x + threadIdx.x;
  if (i < 1024) out[i] = bq[i];
  else if (i < 2048) out[i] = bk[i - 1024];
  else if (i < 3072) out[i] = bv[i - 2048];
}

// ---------------- GEMM (A row-major [M][K], BT row-major [N][K], both bf16) ----------------

template <int EPI>
__global__ __launch_bounds__(256) void k_gemm_bt(
    const unsigned short* __restrict__ A, const unsigned short* __restrict__ BT,
    const float* __restrict__ bias, int K,
    unsigned short* __restrict__ oq, unsigned short* __restrict__ ok,
    unsigned short* __restrict__ ovt, float* __restrict__ of) {
  __shared__ __align__(16) unsigned short Al[128][48];
  __shared__ __align__(16) unsigned short Bl[128][48];
  const int tid = threadIdx.x;
  const int lane = tid & 63, wave = tid >> 6;
  const int wm = wave >> 1, wn = wave & 1;
  const int lr = lane & 15, lg = lane >> 4;
  const int m0 = blockIdx.y * 128, n0 = blockIdx.x * 128;
  f32x4 acc[4][4] = {};
  const int srow = tid >> 2, skc = (tid & 3) * 8;

  for (int k0 = 0; k0 < K; k0 += 32) {
    __syncthreads();
#pragma unroll
    for (int p = 0; p < 2; p++) {
      int row = srow + (p << 6);
      *reinterpret_cast<ushort8*>(&Al[row][skc]) =
          *reinterpret_cast<const ushort8*>(A + (size_t)(m0 + row) * K + k0 + skc);
      *reinterpret_cast<ushort8*>(&Bl[row][skc]) =
          *reinterpret_cast<const ushort8*>(BT + (size_t)(n0 + row) * K + k0 + skc);
    }
    __syncthreads();
    bf16x8 af[4], bfr[4];
#pragma unroll
    for (int i = 0; i < 4; i++)
      af[i] = *reinterpret_cast<const bf16x8*>(&Al[wm * 64 + i * 16 + lr][lg * 8]);
#pragma unroll
    for (int i = 0; i < 4; i++)
      bfr[i] = *reinterpret_cast<const bf16x8*>(&Bl[wn * 64 + i * 16 + lr][lg * 8]);
#pragma unroll
    for (int i = 0; i < 4; i++)
#pragma unroll
      for (int j = 0; j < 4; j++)
        acc[i][j] = mfma16(af[i], bfr[j], acc[i][j]);
  }

#pragma unroll
  for (int i = 0; i < 4; i++) {
#pragma unroll
    for (int j = 0; j < 4; j++) {
      const int n = n0 + wn * 64 + j * 16 + lr;
      const float bv = bias[n];
      const int mb = m0 + wm * 64 + i * 16 + lg * 4;
      if (EPI == 0) {
        const int region = n >> 10;
        const int h = (n & 1023) >> 7, d = n & 127;
        if (region == 2) {
          ushort4v pk;
#pragma unroll
          for (int r = 0; r < 4; r++) pk[r] = f2bf(acc[i][j][r] + bv);
          const int bb = mb >> 11, s = mb & 2047;
          *reinterpret_cast<ushort4v*>(ovt + ((size_t)((bb * NH_ + h) * VD_ + d)) * SS_ + s) = pk;
        } else {
          unsigned short* dst = (region == 0) ? oq : ok;
#pragma unroll
          for (int r = 0; r < 4; r++) {
            const int m = mb + r;
            const int bb = m >> 11, s = m & 2047;
            dst[((size_t)((bb * NH_ + h) * SS_ + s)) * QK_ + d] = f2bf(acc[i][j][r] + bv);
          }
        }
      } else {
#pragma unroll
        for (int r = 0; r < 4; r++) {
          const int m = mb + r;
          of[(size_t)m * DIM_ + n] = acc[i][j][r] + bv;
        }
      }
    }
  }
}

// ---------------- flash attention, S^T structure + in-block split-K ----------------
// grid (32, NH, B), block 512 = 8 waves. Waves 0-3: k-tiles [0,h0) for q-rows
// (sw*16..); waves 4-7: k-tiles [h0,nkt) for the SAME q-rows. One barrier at the
// end merges the two online-softmax partials (exact). 4 waves/SIMD residency.

__global__ __launch_bounds__(512, 4) void k_attn(
    const unsigned short* __restrict__ q, const unsigned short* __restrict__ k,
    const unsigned short* __restrict__ vt, const float* __restrict__ pe,
    unsigned short* __restrict__ att) {
  __shared__ __align__(16) unsigned short P[8][16][72];    // 18 KB, wave-private
  __shared__ __align__(16) unsigned short Xo[4][16][132];  // 16.5 KB, half1 -> half0
  __shared__ float Xml[4][16][2];                          // 0.5 KB

  const int h = blockIdx.y, b = blockIdx.z;
  const int xi = (blockIdx.x + (blockIdx.z << 4)) & 31;
  const int qt = (xi < 16) ? xi : 47 - xi;  // same-CU (z-pair) blocks sum to 33 k-tiles

  const int lane = threadIdx.x & 63, wave = threadIdx.x >> 6;
  const int half = wave >> 2, sw = wave & 3;
  const int lr = lane & 15, lg = lane >> 4;
  const int qrow0 = qt * 64 + sw * 16;
  const int myq = qrow0 + lr;  // this lane's q-row (S^T/O^T layout)

  const unsigned short* qp = q + (size_t)(b * NH_ + h) * SS_ * QK_;
  const unsigned short* kp = k + (size_t)(b * NH_ + h) * SS_ * QK_;
  const unsigned short* vp = vt + (size_t)(b * NH_ + h) * VD_ * SS_;
  const float* pep = pe + (size_t)h * SS_ * SS_ + (size_t)myq * SS_;

  // Q fragments (reused every iteration)
  bf16x8 qf[4];
#pragma unroll
  for (int c = 0; c < 4; c++)
    qf[c] = *reinterpret_cast<const bf16x8*>(qp + (size_t)myq * QK_ + c * 32 + lg * 8);

  f32x4 o[8] = {};  // O^T frags: d = sub*16+lg*4+r, q = myq (unnormalized)
  float m = -1e30f, l = 0.f;
  const float scale = 0.08838834764831845f;  // 1/sqrt(128)

  const int nkt = qt + 1;
  const int h0 = (nkt + 1) >> 1;
  const int kt_lo = half ? h0 : 0;
  const int kt_hi = half ? nkt : h0;

  for (int kt = kt_lo; kt < kt_hi; kt++) {
    const int kbase = kt * 64;

    // V^T fragments, issued first
    bf16x8 vf[2][8];
#pragma unroll
    for (int kk = 0; kk < 2; kk++)
#pragma unroll
      for (int sub = 0; sub < 8; sub++)
        vf[kk][sub] = *reinterpret_cast<const bf16x8*>(
            vp + (size_t)(sub * 16 + lr) * SS_ + kbase + kk * 32 + lg * 8);

    // pe: 4 contiguous float4 per lane (k fast axis)
    f32x4 pe4[4];
#pragma unroll
    for (int ck = 0; ck < 4; ck++)
      pe4[ck] = *reinterpret_cast<const f32x4*>(pep + kbase + ck * 16 + lg * 4);

    // S^T = K * Q^T : sc[ck][r] = S[myq][kbase + ck*16 + lg*4 + r]
    f32x4 sc[4];
#pragma unroll
    for (int ck = 0; ck < 4; ck++) {
      f32x4 a = {};
#pragma unroll
      for (int c = 0; c < 4; c++) {
        const bf16x8 kf = *reinterpret_cast<const bf16x8*>(
            kp + (size_t)(kbase + ck * 16 + lr) * QK_ + c * 32 + lg * 8);
        a = mfma16(kf, qf[c], a);
      }
      sc[ck] = a;
    }

    // scale + pe + causal (diag tile only), in-lane max
    const bool diag = (kt == qt);
    float tm = -1e30f;
#pragma unroll
    for (int ck = 0; ck < 4; ck++) {
#pragma unroll
      for (int r = 0; r < 4; r++) {
        float v = fmaf(sc[ck][r], scale, pe4[ck][r]);
        if (diag && (kbase + ck * 16 + lg * 4 + r) > myq) v = -1e30f;
        sc[ck][r] = v;
        tm = fmaxf(tm, v);
      }
    }
    tm = fmaxf(tm, __shfl_xor(tm, 16));
    tm = fmaxf(tm, __shfl_xor(tm, 32));

    const float mnew = fmaxf(m, tm);
    const float ps = __expf(m - mnew);
    m = mnew;
    float rsum = 0.f;
#pragma unroll
    for (int ck = 0; ck < 4; ck++)
#pragma unroll
      for (int r = 0; r < 4; r++) {
        const float p = __expf(sc[ck][r] - mnew);
        sc[ck][r] = p;
        rsum += p;
      }
    rsum += __shfl_xor(rsum, 16);
    rsum += __shfl_xor(rsum, 32);
    l = l * ps + rsum;
#pragma unroll
    for (int sub = 0; sub < 8; sub++)
#pragma unroll
      for (int r = 0; r < 4; r++) o[sub][r] *= ps;

    // P^T -> wave-private LDS
#pragma unroll
    for (int ck = 0; ck < 4; ck++) {
      ushort4v pk;
#pragma unroll
      for (int r = 0; r < 4; r++) pk[r] = f2bf(sc[ck][r]);
      *reinterpret_cast<ushort4v*>(&P[wave][lr][ck * 16 + lg * 4]) = pk;
    }

    // PV: O^T[d][q] += V^T-frag * P^T-frag
#pragma unroll
    for (int kk = 0; kk < 2; kk++) {
      const bf16x8 pf = *reinterpret_cast<const bf16x8*>(&P[wave][lr][kk * 32 + lg * 8]);
#pragma unroll
      for (int sub = 0; sub < 8; sub++)
        o[sub] = mfma16(vf[kk][sub], pf, o[sub]);
    }
  }

  // half1: publish normalized partial (o/l, m, l) to LDS
  if (half) {
    const float inv = (l > 0.f) ? 1.0f / l : 0.f;
#pragma unroll
    for (int sub = 0; sub < 8; sub++) {
      ushort4v pk;
#pragma unroll
      for (int r = 0; r < 4; r++) pk[r] = f2bf(o[sub][r] * inv);
      *reinterpret_cast<ushort4v*>(&Xo[sw][lr][sub * 16 + lg * 4]) = pk;
    }
    if (lg == 0) { Xml[sw][lr][0] = m; Xml[sw][lr][1] = l; }
  }
  __syncthreads();
  // half0: merge and write
  if (!half) {
    const float m1 = Xml[sw][lr][0], l1 = Xml[sw][lr][1];
    const float ms = fmaxf(m, m1);
    const float w0 = __expf(m - ms);         // applies to unnormalized o
    const float c0 = w0 * l;
    const float c1 = __expf(m1 - ms) * l1;
    const float invT = 1.0f / (c0 + c1);
    unsigned short* ob = att + (size_t)(b * SS_ + myq) * (NH_ * VD_) + h * VD_;
#pragma unroll
    for (int sub = 0; sub < 8; sub++) {
      const ushort4v o1 = *reinterpret_cast<const ushort4v*>(&Xo[sw][lr][sub * 16 + lg * 4]);
      ushort4v pk;
#pragma unroll
      for (int r = 0; r < 4; r++) {
        union { unsigned int u; float f; } cv; cv.u = ((unsigned int)o1[r]) << 16;
        pk[r] = f2bf((w0 * o[sub][r] + c1 * cv.f) * invT);
      }
      *reinterpret_cast<ushort4v*>(ob + sub * 16 + lg * 4) = pk;
    }
  }
}

// ---------------- launcher ----------------

extern "C" void kernel_launch(void* const* d_in, const int* in_sizes, int n_in,
                              void* d_out, int out_size, void* d_ws, size_t ws_size,
                              hipStream_t stream) {
  const float* x    = (const float*)d_in[0];
  const float* pe   = (const float*)d_in[3];
  const float* wq_w = (const float*)d_in[4];
  const float* wq_b = (const float*)d_in[5];
  const float* wk_w = (const float*)d_in[6];
  const float* wk_b = (const float*)d_in[7];
  const float* wv_w = (const float*)d_in[8];
  const float* wv_b = (const float*)d_in[9];
  const float* wo_w = (const float*)d_in[10];
  const float* wo_b = (const float*)d_in[11];
  float* out = (float*)d_out;

  char* ws = (char*)d_ws;
  unsigned short* x_bf   = (unsigned short*)(ws);                 // 4 MB
  unsigned short* wqkv_t = (unsigned short*)(ws + 4194304);       // 3 MB
  unsigned short* wo_t   = (unsigned short*)(ws + 7340032);       // 1 MB
  float*          qkv_b  = (float*)(ws + 8388608);                // 12 KB
  unsigned short* qb     = (unsigned short*)(ws + 8400896);       // 8 MB
  unsigned short* kb     = (unsigned short*)(ws + 16789504);      // 8 MB
  unsigned short* vtb    = (unsigned short*)(ws + 25178112);      // 8 MB
  unsigned short* attb   = (unsigned short*)(ws + 33566720);      // 8 MB

  k_convert_x<<<2048, 256, 0, stream>>>(x, x_bf, (4096 * 512) / 4);
  {
    dim3 gt(16, 8);  // C=1024, R=512
    k_transpose_cvt<<<gt, 256, 0, stream>>>(wq_w, wqkv_t, 512, 1024);
    k_transpose_cvt<<<gt, 256, 0, stream>>>(wk_w, wqkv_t + 1024 * 512, 512, 1024);
    k_transpose_cvt<<<gt, 256, 0, stream>>>(wv_w, wqkv_t + 2048 * 512, 512, 1024);
    dim3 gt2(8, 16);  // C=512, R=1024
    k_transpose_cvt<<<gt2, 256, 0, stream>>>(wo_w, wo_t, 1024, 512);
  }
  k_concat_bias<<<12, 256, 0, stream>>>(wq_b, wk_b, wv_b, qkv_b);

  dim3 g1(24, 32);
  k_gemm_bt<0><<<g1, 256, 0, stream>>>(x_bf, wqkv_t, qkv_b, 512, qb, kb, vtb, nullptr);

  dim3 g2(32, NH_, BB_);
  k_attn<<<g2, 512, 0, stream>>>(qb, kb, vtb, pe, attb);

  dim3 g3(4, 32);
  k_gemm_bt<1><<<g3, 256, 0, stream>>>(attb, wo_t, wo_b, 1024, nullptr, nullptr, nullptr, out);
}